// Round 7
// baseline (264.223 us; speedup 1.0000x reference)
//
#include <hip/hip_runtime.h>
#include <stdint.h>

#define BATCH 32768
#define DIM   512
#define KCLS  512

typedef __bf16    bf16x8 __attribute__((ext_vector_type(8)));
typedef float     f32x4  __attribute__((ext_vector_type(4)));
typedef float     f32x8  __attribute__((ext_vector_type(8)));
typedef uint16_t  u16x8  __attribute__((ext_vector_type(8)));

__device__ __forceinline__ uint16_t f2bf(float f) {
    // RTNE fp32 -> bf16
    uint32_t u = __float_as_uint(f);
    u += 0x7FFFu + ((u >> 16) & 1u);
    return (uint16_t)(u >> 16);
}

// convert f32x8 -> bf16x8 (RTNE), accumulating sum of squares
__device__ __forceinline__ bf16x8 cvt8(const f32x8 v, float& xsq) {
    u16x8 p;
    #pragma unroll
    for (int j = 0; j < 8; ++j) { xsq += v[j] * v[j]; p[j] = f2bf(v[j]); }
    return __builtin_bit_cast(bf16x8, p);
}

#define MFMA(a, b, c) __builtin_amdgcn_mfma_f32_16x16x32_bf16((a), (b), (c), 0, 0, 0)

// ---------------------------------------------------------------------------
// Prep: means (K x D fp32) -> bf16 pre-swizzled into MFMA B-fragment order.
// B-frag for mfma_f32_16x16x32_bf16: B[k = 8*(lane>>4)+j][n = lane&15].
// Bsw layout: index = (((c16*16 + ch)*64) + lane)*8, col = 16*c16 + (lane&15),
// k = 32*ch + 8*(lane>>4) + j.  Also computes inv_var/alpha/beta per class.
// ---------------------------------------------------------------------------
__global__ __launch_bounds__(256) void gmm_prep(
    const float* __restrict__ means,
    const float* __restrict__ log_vars,
    const float* __restrict__ log_weights,
    uint16_t* __restrict__ Bsw,
    float* __restrict__ invv_a,
    float* __restrict__ alpha_a,
    float* __restrict__ beta_a)
{
    const int k = blockIdx.x * 4 + (threadIdx.x >> 6);  // class index
    const int l = threadIdx.x & 63;                     // lane: elems 8l..8l+7

    const float* mrow = means + (size_t)k * DIM + l * 8;
    f32x4 v0 = *(const f32x4*)(mrow);
    f32x4 v1 = *(const f32x4*)(mrow + 4);

    u16x8 pk;
    pk[0] = f2bf(v0[0]); pk[1] = f2bf(v0[1]); pk[2] = f2bf(v0[2]); pk[3] = f2bf(v0[3]);
    pk[4] = f2bf(v1[0]); pk[5] = f2bf(v1[1]); pk[6] = f2bf(v1[2]); pk[7] = f2bf(v1[3]);

    const int c16 = k >> 4, r = k & 15, ch = l >> 2, hh = l & 3;
    *(u16x8*)(Bsw + ((((c16 * 16) + ch) * 64) + (hh * 16 + r)) * 8) = pk;

    float sq = v0[0]*v0[0] + v0[1]*v0[1] + v0[2]*v0[2] + v0[3]*v0[3]
             + v1[0]*v1[0] + v1[1]*v1[1] + v1[2]*v1[2] + v1[3]*v1[3];
    #pragma unroll
    for (int m = 1; m <= 32; m <<= 1) sq += __shfl_xor(sq, m);

    if (l == 0) {
        const float lv = log_vars[k];
        const float iv = __expf(-lv);
        invv_a[k]  = iv;
        alpha_a[k] = -0.5f * iv;
        beta_a[k]  = -0.5f * (sq * iv + (float)DIM * lv) + log_weights[k];
    }
}

// ---------------------------------------------------------------------------
// Main fused kernel, R9: NO LDS STAGING of A — barrier-free K-loop.
// Post-mortem R5-R8: every restructure of the LDS-staged pipeline lost to
// R4's 47us via occupancy loss or allocator spills (R8: VGPR 84 reported yet
// +80MB scratch traffic). Root cause: the staging machinery itself (serial
// HBM burst, per-phase barriers locksteping waves, LDS write/read liveness).
// R9 removes it: the A-fragment is lane (r16,h) holding
// x[row0+16rt+r16][32c+8h..+7] — a contiguous f32x8 DIRECTLY from x
// (per instr: 16 rows x 128B contiguous segments, fully coalesced).
// 4 waves redundantly load/convert the same tile (~+190MB L2, ~5us L2 pipe,
// overlapped; conversion ~112 VALU cyc/chunk/wave, trivial) in exchange for:
//   * zero barriers until epilogue -> waves drift, stalls covered by TLP
//     (the mechanism R7 proved is blocked while barrier-locked)
//   * x-read, B-stream, cvt, MFMA merged in one loop -> no serial phases
//   * registers: Ba rotate 32 + raw-A dist-2 dbuf 32 + A 8 + xsq 2 + addr
//     ~15 = ~95 arch + 64 acc = 159 <= 170 -> 3 waves/SIMD at (256,3).
// xsq computed during conversion (h-slice per lane), reduced via
// shfl_xor(16,32), redistributed through 128B of LDS at the epilogue.
// Failure watch: WRITE>75MB = spill; FETCH>100MB = L1/L2 reuse miss.
// (Round-6 bench died on infra — container failed twice, no counters.
//  Kernel re-audited: bounds exact, barriers uniform, pipeline bookkeeping
//  verified. Resubmitting unchanged, as with the R4->R5 infra retry.)
// ---------------------------------------------------------------------------
__global__ __launch_bounds__(256, 3) void gmm_main(
    const float* __restrict__ x,
    const uint16_t* __restrict__ Bsw,
    const float* __restrict__ invv_a,
    const float* __restrict__ alpha_a,
    const float* __restrict__ beta_a,
    float* __restrict__ out)
{
    __shared__ float xsq_lds[32];
    __shared__ float pmax[4][32];
    __shared__ float psum[4][32];

    const int t    = threadIdx.x;
    const int w    = t >> 6;        // wave -> col group (128 cols)
    const int lane = t & 63;
    const int r16  = lane & 15;
    const int h    = lane >> 4;
    const int row0 = blockIdx.x * 32;

    // A source: lane (r16,h) reads x[row0+16rt+r16][32c+8h..+7] directly
    const float* xa = x + (size_t)(row0 + r16) * DIM + 8 * h;   // rt=0; rt=1: +16*DIM
    const uint16_t* bb = Bsw + (size_t)w * 65536 + (size_t)lane * 8;

    f32x4 acc[2][8];
    #pragma unroll
    for (int rt = 0; rt < 2; ++rt)
        #pragma unroll
        for (int ct = 0; ct < 8; ++ct)
            acc[rt][ct] = (f32x4){0.f, 0.f, 0.f, 0.f};

    // ---- prologue: raw A chunks 0,1; B chunk 0; cvt chunk 0; raw chunk 2 ----
    f32x8 Rr[2][2];                       // [chunk parity][rt]
    Rr[0][0] = *(const f32x8*)(xa);
    Rr[0][1] = *(const f32x8*)(xa + 16 * DIM);
    Rr[1][0] = *(const f32x8*)(xa + 32);
    Rr[1][1] = *(const f32x8*)(xa + 16 * DIM + 32);

    bf16x8 Ba[8];
    #pragma unroll
    for (int ct = 0; ct < 8; ++ct) Ba[ct] = *(const bf16x8*)(bb + ct * 8192);

    float xsq0 = 0.f, xsq1 = 0.f;
    bf16x8 A0 = cvt8(Rr[0][0], xsq0);
    bf16x8 A1 = cvt8(Rr[0][1], xsq1);
    Rr[0][0] = *(const f32x8*)(xa + 64);
    Rr[0][1] = *(const f32x8*)(xa + 16 * DIM + 64);

    // ---- barrier-free K-loop: 16 chunks ----
    // chunk c: MFMA(A, Ba) + rotate Ba -> c+1; cvt c+1 from Rr[(c+1)&1];
    // issue raw load c+3 into the freed buffer (distance-2 cover).
    #pragma unroll
    for (int c = 0; c < 16; ++c) {
        #pragma unroll
        for (int ct = 0; ct < 8; ++ct) {
            acc[0][ct] = MFMA(A0, Ba[ct], acc[0][ct]);
            acc[1][ct] = MFMA(A1, Ba[ct], acc[1][ct]);
            if (c < 15) Ba[ct] = *(const bf16x8*)(bb + ct * 8192 + (c + 1) * 512);
        }
        if (c < 15) {
            const int pr = (c + 1) & 1;
            A0 = cvt8(Rr[pr][0], xsq0);
            A1 = cvt8(Rr[pr][1], xsq1);
            if (c < 13) {
                Rr[pr][0] = *(const f32x8*)(xa + 32 * (c + 3));
                Rr[pr][1] = *(const f32x8*)(xa + 16 * DIM + 32 * (c + 3));
            }
        }
    }

    // ---- xsq: reduce over h-groups (lane bits 4,5), redistribute via LDS ----
    xsq0 += __shfl_xor(xsq0, 16);
    xsq0 += __shfl_xor(xsq0, 32);
    xsq1 += __shfl_xor(xsq1, 16);
    xsq1 += __shfl_xor(xsq1, 32);
    if (lane < 16) {                      // all waves write identical values
        xsq_lds[r16]      = xsq0;
        xsq_lds[16 + r16] = xsq1;
    }
    __syncthreads();

    // ---- per-column affine params (L2-hot; after K-loop on purpose) ----
    float invv[8], alf[8], bet[8];
    #pragma unroll
    for (int ct = 0; ct < 8; ++ct) {
        const int col = 128 * w + 16 * ct + r16;
        invv[ct] = invv_a[col];
        alf[ct]  = alpha_a[col];
        bet[ct]  = beta_a[col];
    }
    float xsq[2][4];
    #pragma unroll
    for (int rt = 0; rt < 2; ++rt)
        #pragma unroll
        for (int reg = 0; reg < 4; ++reg)
            xsq[rt][reg] = xsq_lds[16 * rt + 4 * h + reg];

    // ---- logits + per-row max (C layout: col=lane&15, row=4*(lane>>4)+reg) ----
    float mr[2][4];
    #pragma unroll
    for (int rt = 0; rt < 2; ++rt) {
        #pragma unroll
        for (int reg = 0; reg < 4; ++reg) {
            float m = -1e30f;
            #pragma unroll
            for (int ct = 0; ct < 8; ++ct) {
                const float v = acc[rt][ct][reg] * invv[ct] + (alf[ct] * xsq[rt][reg] + bet[ct]);
                acc[rt][ct][reg] = v;
                m = fmaxf(m, v);
            }
            m = fmaxf(m, __shfl_xor(m, 1));
            m = fmaxf(m, __shfl_xor(m, 2));
            m = fmaxf(m, __shfl_xor(m, 4));
            m = fmaxf(m, __shfl_xor(m, 8));
            mr[rt][reg] = m;
        }
    }
    if (r16 == 0) {
        #pragma unroll
        for (int rt = 0; rt < 2; ++rt)
            #pragma unroll
            for (int reg = 0; reg < 4; ++reg)
                pmax[w][16 * rt + 4 * h + reg] = mr[rt][reg];
    }
    __syncthreads();

    // ---- exp + per-row sum ----
    float sr[2][4];
    #pragma unroll
    for (int rt = 0; rt < 2; ++rt) {
        #pragma unroll
        for (int reg = 0; reg < 4; ++reg) {
            const int rl = 16 * rt + 4 * h + reg;
            const float m = fmaxf(fmaxf(pmax[0][rl], pmax[1][rl]),
                                  fmaxf(pmax[2][rl], pmax[3][rl]));
            float s = 0.f;
            #pragma unroll
            for (int ct = 0; ct < 8; ++ct) {
                const float e = __expf(acc[rt][ct][reg] - m);
                acc[rt][ct][reg] = e;
                s += e;
            }
            s += __shfl_xor(s, 1);
            s += __shfl_xor(s, 2);
            s += __shfl_xor(s, 4);
            s += __shfl_xor(s, 8);
            sr[rt][reg] = s;
        }
    }
    if (r16 == 0) {
        #pragma unroll
        for (int rt = 0; rt < 2; ++rt)
            #pragma unroll
            for (int reg = 0; reg < 4; ++reg)
                psum[w][16 * rt + 4 * h + reg] = sr[rt][reg];
    }
    __syncthreads();

    // ---- normalize + store ----
    #pragma unroll
    for (int rt = 0; rt < 2; ++rt) {
        #pragma unroll
        for (int reg = 0; reg < 4; ++reg) {
            const int rl = 16 * rt + 4 * h + reg;
            const float tot = (psum[0][rl] + psum[1][rl]) + (psum[2][rl] + psum[3][rl]);
            const float rinv = 1.0f / tot;
            float* orow = out + (size_t)(row0 + rl) * KCLS + 128 * w + r16;
            #pragma unroll
            for (int ct = 0; ct < 8; ++ct)
                orow[16 * ct] = acc[rt][ct][reg] * rinv;
        }
    }
}

extern "C" void kernel_launch(void* const* d_in, const int* in_sizes, int n_in,
                              void* d_out, int out_size, void* d_ws, size_t ws_size,
                              hipStream_t stream) {
    (void)in_sizes; (void)n_in; (void)out_size; (void)ws_size;
    const float* x           = (const float*)d_in[0];
    const float* means       = (const float*)d_in[1];
    const float* log_vars    = (const float*)d_in[2];
    const float* log_weights = (const float*)d_in[3];
    float* out = (float*)d_out;

    // ws: [0, 512KB) swizzled bf16 means; then inv_var/alpha/beta (512 f32 each)
    uint16_t* Bsw = (uint16_t*)d_ws;
    float* invv_a  = (float*)((char*)d_ws + (512u << 10));
    float* alpha_a = invv_a + KCLS;
    float* beta_a  = alpha_a + KCLS;

    gmm_prep<<<KCLS / 4, 256, 0, stream>>>(means, log_vars, log_weights,
                                           Bsw, invv_a, alpha_a, beta_a);
    gmm_main<<<BATCH / 32, 256, 0, stream>>>(x, Bsw, invv_a, alpha_a, beta_a, out);
}

// Round 8
// 135.533 us; speedup vs baseline: 1.9495x; 1.9495x over previous
//
#include <hip/hip_runtime.h>
#include <stdint.h>

#define BATCH 32768
#define DIM   512
#define KCLS  512

typedef __bf16    bf16x8 __attribute__((ext_vector_type(8)));
typedef float     f32x4  __attribute__((ext_vector_type(4)));
typedef float     f32x8  __attribute__((ext_vector_type(8)));
typedef uint16_t  u16x8  __attribute__((ext_vector_type(8)));

__device__ __forceinline__ uint16_t f2bf(float f) {
    // RTNE fp32 -> bf16
    uint32_t u = __float_as_uint(f);
    u += 0x7FFFu + ((u >> 16) & 1u);
    return (uint16_t)(u >> 16);
}

#define MFMA(a, b, c) __builtin_amdgcn_mfma_f32_16x16x32_bf16((a), (b), (c), 0, 0, 0)

// ---------------------------------------------------------------------------
// Prep: means (K x D fp32) -> bf16 pre-swizzled into MFMA B-fragment order.
// B-frag for mfma_f32_16x16x32_bf16: B[k = 8*(lane>>4)+j][n = lane&15].
// Bsw layout: index = (((c16*16 + ch)*64) + lane)*8, col = 16*c16 + (lane&15),
// k = 32*ch + 8*(lane>>4) + j.  Also computes inv_var/alpha/beta per class.
// ---------------------------------------------------------------------------
__global__ __launch_bounds__(256) void gmm_prep(
    const float* __restrict__ means,
    const float* __restrict__ log_vars,
    const float* __restrict__ log_weights,
    uint16_t* __restrict__ Bsw,
    float* __restrict__ invv_a,
    float* __restrict__ alpha_a,
    float* __restrict__ beta_a)
{
    const int k = blockIdx.x * 4 + (threadIdx.x >> 6);  // class index
    const int l = threadIdx.x & 63;                     // lane: elems 8l..8l+7

    const float* mrow = means + (size_t)k * DIM + l * 8;
    f32x4 v0 = *(const f32x4*)(mrow);
    f32x4 v1 = *(const f32x4*)(mrow + 4);

    u16x8 pk;
    pk[0] = f2bf(v0[0]); pk[1] = f2bf(v0[1]); pk[2] = f2bf(v0[2]); pk[3] = f2bf(v0[3]);
    pk[4] = f2bf(v1[0]); pk[5] = f2bf(v1[1]); pk[6] = f2bf(v1[2]); pk[7] = f2bf(v1[3]);

    const int c16 = k >> 4, r = k & 15, ch = l >> 2, hh = l & 3;
    *(u16x8*)(Bsw + ((((c16 * 16) + ch) * 64) + (hh * 16 + r)) * 8) = pk;

    float sq = v0[0]*v0[0] + v0[1]*v0[1] + v0[2]*v0[2] + v0[3]*v0[3]
             + v1[0]*v1[0] + v1[1]*v1[1] + v1[2]*v1[2] + v1[3]*v1[3];
    #pragma unroll
    for (int m = 1; m <= 32; m <<= 1) sq += __shfl_xor(sq, m);

    if (l == 0) {
        const float lv = log_vars[k];
        const float iv = __expf(-lv);
        invv_a[k]  = iv;
        alpha_a[k] = -0.5f * iv;
        beta_a[k]  = -0.5f * (sq * iv + (float)DIM * lv) + log_weights[k];
    }
}

// ---------------------------------------------------------------------------
// Main fused kernel, R10 = R4 (the verified 47us/135us optimum) + one
// allocation-neutral tweak: chunk-0 B prefetch hoisted ABOVE the staging
// barrier, so the K-loop's first 8 L2 loads complete under the ~10us
// staging phase instead of serializing after the barrier.
// Session ledger (why this is R4 again): five restructures all lost to
// allocator/occupancy behavior —
//   R5 64-row/256thr: 2 blk/CU, 55us. R6 64-row/512thr cap128: spill, 91us.
//   R7 (256,4) cap128: spill, 70us. R8 fused-stage: spill, 82us.
//   R9 barrier-free no-LDS: VGPR 84 but ~780B/thread scratch, 180us.
// Conclusion: hipcc only compiles THIS structure cleanly (104 VGPR + 64
// AGPR, zero scratch, 3 waves/SIMD). Peak pressure is in the K-loop, so
// +32 VGPR (Ba) during the low-pressure staging section changes nothing.
// ---------------------------------------------------------------------------
__global__ __launch_bounds__(256, 2) void gmm_main(
    const float* __restrict__ x,
    const uint16_t* __restrict__ Bsw,
    const float* __restrict__ invv_a,
    const float* __restrict__ alpha_a,
    const float* __restrict__ beta_a,
    float* __restrict__ out)
{
    __shared__ uint16_t As[16384];   // 32 KB
    __shared__ float xsq_lds[32];
    __shared__ float pmax[4][32];
    __shared__ float psum[4][32];

    const int t    = threadIdx.x;
    const int w    = t >> 6;        // wave -> col group
    const int lane = t & 63;
    const int r16  = lane & 15;
    const int h    = lane >> 4;
    const int row0 = blockIdx.x * 32;

    // ---- B chunk-0 prefetch issued FIRST: completes under the x-stage ----
    const uint16_t* bb = Bsw + (size_t)w * 65536 + (size_t)lane * 8;
    bf16x8 Ba[8], Bb[8];
    #pragma unroll
    for (int ct = 0; ct < 8; ++ct) Ba[ct] = *(const bf16x8*)(bb + ct * 8192);

    // ---- stage x tile -> LDS (fragment order) + xsq ----
    {
        const int srow = t >> 3, sp = t & 7;         // 8 threads per row
        const int rt_s = srow >> 4, r16_s = srow & 15;
        const float* xr = x + (size_t)(row0 + srow) * DIM;
        float xsq_p = 0.f;
        #pragma unroll
        for (int i = 0; i < 8; ++i) {
            const int o = sp + 8 * i;                // k-octet 0..63
            f32x8 v = *(const f32x8*)(xr + 8 * o);
            u16x8 pk;
            #pragma unroll
            for (int j = 0; j < 8; ++j) { xsq_p += v[j] * v[j]; pk[j] = f2bf(v[j]); }
            const int c = o >> 2, hh = o & 3;
            *(u16x8*)&As[(((c * 2 + rt_s) * 64) + hh * 16 + r16_s) * 8] = pk;
        }
        xsq_p += __shfl_xor(xsq_p, 1);
        xsq_p += __shfl_xor(xsq_p, 2);
        xsq_p += __shfl_xor(xsq_p, 4);
        if (sp == 0) xsq_lds[srow] = xsq_p;
    }
    __syncthreads();

    f32x4 acc[2][8];
    #pragma unroll
    for (int rt = 0; rt < 2; ++rt)
        #pragma unroll
        for (int ct = 0; ct < 8; ++ct)
            acc[rt][ct] = (f32x4){0.f, 0.f, 0.f, 0.f};

    const uint16_t* ab = As + (size_t)lane * 8;     // LDS, frag base

    // ---- software-pipelined K-loop (16 chunks, 2 per unrolled iter) ----
    bf16x8 Aa0, Aa1, Ab0, Ab1;
    Aa0 = *(const bf16x8*)(ab);
    Aa1 = *(const bf16x8*)(ab + 512);

    #pragma unroll
    for (int c2 = 0; c2 < 8; ++c2) {
        const int k1 = 2 * c2 + 1, k2 = 2 * c2 + 2;

        // A prefetch for k1 (LDS), then B-prefetch interleaved 1:1 with MFMAs
        Ab0 = *(const bf16x8*)(ab + k1 * 1024);
        Ab1 = *(const bf16x8*)(ab + k1 * 1024 + 512);
        #pragma unroll
        for (int ct = 0; ct < 8; ++ct) {
            Bb[ct] = *(const bf16x8*)(bb + ct * 8192 + k1 * 512);
            acc[0][ct] = MFMA(Aa0, Ba[ct], acc[0][ct]);
            acc[1][ct] = MFMA(Aa1, Ba[ct], acc[1][ct]);
        }

        if (c2 < 7) {
            Aa0 = *(const bf16x8*)(ab + k2 * 1024);
            Aa1 = *(const bf16x8*)(ab + k2 * 1024 + 512);
        }
        #pragma unroll
        for (int ct = 0; ct < 8; ++ct) {
            if (c2 < 7) Ba[ct] = *(const bf16x8*)(bb + ct * 8192 + k2 * 512);
            acc[0][ct] = MFMA(Ab0, Bb[ct], acc[0][ct]);
            acc[1][ct] = MFMA(Ab1, Bb[ct], acc[1][ct]);
        }
    }

    // ---- per-column affine params (L2-hot) ----
    float invv[8], alf[8], bet[8];
    #pragma unroll
    for (int ct = 0; ct < 8; ++ct) {
        const int col = 128 * w + 16 * ct + r16;
        invv[ct] = invv_a[col];
        alf[ct]  = alpha_a[col];
        bet[ct]  = beta_a[col];
    }
    float xsq[2][4];
    #pragma unroll
    for (int rt = 0; rt < 2; ++rt)
        #pragma unroll
        for (int reg = 0; reg < 4; ++reg)
            xsq[rt][reg] = xsq_lds[16 * rt + 4 * h + reg];

    // ---- logits + per-row max (C layout: col=lane&15, row=4*(lane>>4)+reg) ----
    float mr[2][4];
    #pragma unroll
    for (int rt = 0; rt < 2; ++rt) {
        #pragma unroll
        for (int reg = 0; reg < 4; ++reg) {
            float m = -1e30f;
            #pragma unroll
            for (int ct = 0; ct < 8; ++ct) {
                const float v = acc[rt][ct][reg] * invv[ct] + (alf[ct] * xsq[rt][reg] + bet[ct]);
                acc[rt][ct][reg] = v;
                m = fmaxf(m, v);
            }
            m = fmaxf(m, __shfl_xor(m, 1));
            m = fmaxf(m, __shfl_xor(m, 2));
            m = fmaxf(m, __shfl_xor(m, 4));
            m = fmaxf(m, __shfl_xor(m, 8));
            mr[rt][reg] = m;
        }
    }
    if (r16 == 0) {
        #pragma unroll
        for (int rt = 0; rt < 2; ++rt)
            #pragma unroll
            for (int reg = 0; reg < 4; ++reg)
                pmax[w][16 * rt + 4 * h + reg] = mr[rt][reg];
    }
    __syncthreads();

    // ---- exp + per-row sum ----
    float sr[2][4];
    #pragma unroll
    for (int rt = 0; rt < 2; ++rt) {
        #pragma unroll
        for (int reg = 0; reg < 4; ++reg) {
            const int rl = 16 * rt + 4 * h + reg;
            const float m = fmaxf(fmaxf(pmax[0][rl], pmax[1][rl]),
                                  fmaxf(pmax[2][rl], pmax[3][rl]));
            float s = 0.f;
            #pragma unroll
            for (int ct = 0; ct < 8; ++ct) {
                const float e = __expf(acc[rt][ct][reg] - m);
                acc[rt][ct][reg] = e;
                s += e;
            }
            s += __shfl_xor(s, 1);
            s += __shfl_xor(s, 2);
            s += __shfl_xor(s, 4);
            s += __shfl_xor(s, 8);
            sr[rt][reg] = s;
        }
    }
    if (r16 == 0) {
        #pragma unroll
        for (int rt = 0; rt < 2; ++rt)
            #pragma unroll
            for (int reg = 0; reg < 4; ++reg)
                psum[w][16 * rt + 4 * h + reg] = sr[rt][reg];
    }
    __syncthreads();

    // ---- normalize + store ----
    #pragma unroll
    for (int rt = 0; rt < 2; ++rt) {
        #pragma unroll
        for (int reg = 0; reg < 4; ++reg) {
            const int rl = 16 * rt + 4 * h + reg;
            const float tot = (psum[0][rl] + psum[1][rl]) + (psum[2][rl] + psum[3][rl]);
            const float rinv = 1.0f / tot;
            float* orow = out + (size_t)(row0 + rl) * KCLS + 128 * w + r16;
            #pragma unroll
            for (int ct = 0; ct < 8; ++ct)
                orow[16 * ct] = acc[rt][ct][reg] * rinv;
        }
    }
}

extern "C" void kernel_launch(void* const* d_in, const int* in_sizes, int n_in,
                              void* d_out, int out_size, void* d_ws, size_t ws_size,
                              hipStream_t stream) {
    (void)in_sizes; (void)n_in; (void)out_size; (void)ws_size;
    const float* x           = (const float*)d_in[0];
    const float* means       = (const float*)d_in[1];
    const float* log_vars    = (const float*)d_in[2];
    const float* log_weights = (const float*)d_in[3];
    float* out = (float*)d_out;

    // ws: [0, 512KB) swizzled bf16 means; then inv_var/alpha/beta (512 f32 each)
    uint16_t* Bsw = (uint16_t*)d_ws;
    float* invv_a  = (float*)((char*)d_ws + (512u << 10));
    float* alpha_a = invv_a + KCLS;
    float* beta_a  = alpha_a + KCLS;

    gmm_prep<<<KCLS / 4, 256, 0, stream>>>(means, log_vars, log_weights,
                                           Bsw, invv_a, alpha_a, beta_a);
    gmm_main<<<BATCH / 32, 256, 0, stream>>>(x, Bsw, invv_a, alpha_a, beta_a, out);
}